// Round 1
// baseline (113.038 us; speedup 1.0000x reference)
//
#include <hip/hip_runtime.h>

typedef float  f32x4  __attribute__((ext_vector_type(4)));
typedef short  bf16x8 __attribute__((ext_vector_type(8)));

#define NT   16384   // BATCH*SEQ tokens
#define GRID 512     // 1 wave per block, 2 blocks/CU (64KB LDS each)

__device__ __forceinline__ short f2bf(float x) {
  unsigned u = __builtin_bit_cast(unsigned, x);
  u = (u + 0x7FFFu + ((u >> 16) & 1u)) >> 16;   // RNE
  return (short)u;
}

__device__ __forceinline__ void gload16(const float* gp, float* lp) {
  __builtin_amdgcn_global_load_lds((const __attribute__((address_space(1))) void*)gp,
                                   (__attribute__((address_space(3))) void*)lp,
                                   16, 0, 0);
}

// Stage one token's X (64x64 fp32 = 16KB) into LDS, 16 x global_load_lds(16B).
// LDS dest is linear; the XOR swizzle (16B-chunk granularity, q ^= i&7) is applied
// to the GLOBAL source so fragment ds_read_b128s are bank-conflict-free.
__device__ __forceinline__ void stage(float (&XB)[4096], const float* gbase, int lane) {
#pragma unroll
  for (int q = 0; q < 16; ++q) {
    const int i  = q * 4 + (lane >> 4);
    const int qp = lane & 15;
    const float* gp = gbase + i * 64 + ((qp ^ (i & 7)) << 2);
    gload16(gp, &XB[0] + q * 256);
  }
}

__device__ __forceinline__ void body(float (&XB)[4096],
                                     bf16x8 (&AT)[1024], bf16x8 (&BT)[1024],
                                     int tok, int lane, int g, int l15,
                                     const float* __restrict__ x,
                                     const float* __restrict__ bias,
                                     float* __restrict__ out) {
  // Steady state outstanding at this point: [this tok's 16 loads](oldest) +
  // prev stage(16) + prev bias(16) + prev stores(16) = 64 -> vmcnt(48) drains
  // exactly this token's X loads, keeps the newer prefetch in flight.
  asm volatile("s_waitcnt vmcnt(48)" ::: "memory");

  const f32x4* xb4 = (const f32x4*)(&XB[0]);

  // X fragments (A-op of stage 1): lane row i = 16*it + l15, k = j = 32*jc + 8g + e
  bf16x8 xf[4][2];
#pragma unroll
  for (int it = 0; it < 4; ++it) {
#pragma unroll
    for (int jc = 0; jc < 2; ++jc) {
      const int i  = it * 16 + l15;
      const int q0 = jc * 8 + 2 * g;
      f32x4 f0 = xb4[i * 16 + ((q0    ) ^ (i & 7))];
      f32x4 f1 = xb4[i * 16 + ((q0 + 1) ^ (i & 7))];
      bf16x8 t;
      t[0]=f2bf(f0.x); t[1]=f2bf(f0.y); t[2]=f2bf(f0.z); t[3]=f2bf(f0.w);
      t[4]=f2bf(f1.x); t[5]=f2bf(f1.y); t[6]=f2bf(f1.z); t[7]=f2bf(f1.w);
      xf[it][jc] = t;
    }
  }

  f32x4 acc2[4][4];
#pragma unroll
  for (int a = 0; a < 4; ++a)
#pragma unroll
    for (int b = 0; b < 4; ++b)
      acc2[a][b] = (f32x4){0.f, 0.f, 0.f, 0.f};

#pragma unroll
  for (int s = 0; s < 2; ++s) {
    // B fragments (B-op of stage 1): lane col p = 16*pt + l15, k = j = 32*jc+8g+e
    bf16x8 bfr[4][2];
#pragma unroll
    for (int pt = 0; pt < 4; ++pt)
#pragma unroll
      for (int jc = 0; jc < 2; ++jc)
        bfr[pt][jc] = BT[(s * 8 + pt * 2 + jc) * 64 + lane];

    // Stage 1: U = X * B_s^T.  D tile (it,pt): lane holds col p=l15, rows i=4g+r.
    f32x4 a1[4][4];
#pragma unroll
    for (int a = 0; a < 4; ++a)
#pragma unroll
      for (int b = 0; b < 4; ++b)
        a1[a][b] = (f32x4){0.f, 0.f, 0.f, 0.f};
#pragma unroll
    for (int it = 0; it < 4; ++it)
#pragma unroll
      for (int pt = 0; pt < 4; ++pt)
#pragma unroll
        for (int jc = 0; jc < 2; ++jc)
          a1[it][pt] = __builtin_amdgcn_mfma_f32_16x16x32_bf16(
              xf[it][jc], bfr[pt][jc], a1[it][pt], 0, 0, 0);

    // Repack U (in-lane): stage-2 A-op element e of chunk c is
    // U[i = 4g + (e&3) + 16*(e>>2) + 32c][p], i.e. a1[it=(e>>2)+2c][pt] reg (e&3).
    bf16x8 uf[4][2];
#pragma unroll
    for (int pt = 0; pt < 4; ++pt)
#pragma unroll
      for (int c = 0; c < 2; ++c) {
        bf16x8 t;
#pragma unroll
        for (int e = 0; e < 8; ++e)
          t[e] = f2bf(a1[(e >> 2) + 2 * c][pt][e & 3]);
        uf[pt][c] = t;
      }

    // A fragments (B-op of stage 2), same sigma2 permutation baked into the table.
    bf16x8 afr[4][2];
#pragma unroll
    for (int ot = 0; ot < 4; ++ot)
#pragma unroll
      for (int c = 0; c < 2; ++c)
        afr[ot][c] = AT[(s * 8 + ot * 2 + c) * 64 + lane];

    // Stage 2: Y^T-tiles. D tile (pt,ot): lane holds col o=l15, rows p=4g+r.
#pragma unroll
    for (int pt = 0; pt < 4; ++pt)
#pragma unroll
      for (int ot = 0; ot < 4; ++ot)
#pragma unroll
        for (int c = 0; c < 2; ++c)
          acc2[pt][ot] = __builtin_amdgcn_mfma_f32_16x16x32_bf16(
              uf[pt][c], afr[ot][c], acc2[pt][ot], 0, 0, 0);
  }

  // Bias loads BEFORE the prefetch stage, so the compiler's bias-dependency
  // vmcnt waits never drain the prefetch queue.
  const int pcol = 4 * g;
  f32x4 bv[4][4];
#pragma unroll
  for (int pt = 0; pt < 4; ++pt)
#pragma unroll
    for (int ot = 0; ot < 4; ++ot)
      bv[pt][ot] = *(const f32x4*)(bias + (ot * 16 + l15) * 64 + pt * 16 + pcol);

  asm volatile("" ::: "memory");
  stage(XB, x + ((size_t)((tok + 2 * GRID) & (NT - 1)) << 12), lane);
  asm volatile("" ::: "memory");

  float* ob = out + ((size_t)tok << 12);
#pragma unroll
  for (int pt = 0; pt < 4; ++pt)
#pragma unroll
    for (int ot = 0; ot < 4; ++ot) {
      f32x4 r = acc2[pt][ot] + bv[pt][ot];
      *(f32x4*)(ob + (ot * 16 + l15) * 64 + pt * 16 + pcol) = r;
    }
}

__global__ __launch_bounds__(64) void kron_kernel(const float* __restrict__ x,
                                                  const float* __restrict__ A,
                                                  const float* __restrict__ B,
                                                  const float* __restrict__ bias,
                                                  float* __restrict__ out) {
  __shared__ float  xb0[4096];     // 16KB  token X buffer A (fp32, swizzled chunks)
  __shared__ float  xb1[4096];     // 16KB  token X buffer B
  __shared__ bf16x8 AT[1024];      // 16KB  A-frag stream [s*8+ot*2+c][lane]
  __shared__ bf16x8 BT[1024];      // 16KB  B-frag stream [s*8+pt*2+jc][lane]

  const int lane = threadIdx.x;
  const int g    = lane >> 4;
  const int l15  = lane & 15;
  const int bid  = blockIdx.x;

  // Build operand fragment tables once per block (single wave: no barrier needed).
  for (int idx = 0; idx < 16; ++idx) {           // A: idx = s*8 + ot*2 + c
    const int s = idx >> 3, ot = (idx & 7) >> 1, c = idx & 1;
    const int o = ot * 16 + l15;
    bf16x8 v;
#pragma unroll
    for (int e = 0; e < 8; ++e) {
      const int i = c * 32 + 4 * g + (e & 3) + 16 * (e >> 2);   // sigma2
      v[e] = f2bf(A[s * 4096 + o * 64 + i]);
    }
    AT[idx * 64 + lane] = v;
  }
  for (int idx = 0; idx < 16; ++idx) {           // B: idx = s*8 + pt*2 + jc
    const int s = idx >> 3, pt = (idx & 7) >> 1, jc = idx & 1;
    const int p = pt * 16 + l15;
    bf16x8 v;
#pragma unroll
    for (int e = 0; e < 8; ++e) {
      const int j = jc * 32 + 8 * g + e;                        // sigma1 (contiguous)
      v[e] = f2bf(B[s * 4096 + p * 64 + j]);
    }
    BT[idx * 64 + lane] = v;
  }

  // Prologue: prefetch first two tokens, ensure token0 is resident.
  stage(xb0, x + ((size_t)bid << 12), lane);
  stage(xb1, x + ((size_t)(bid + GRID) << 12), lane);
  asm volatile("s_waitcnt vmcnt(16)" ::: "memory");

  // 32 tokens per wave, strided; each body computes tok from its buffer and
  // prefetches tok+1024 into the same buffer (consumed two bodies later).
  for (int k = 0; k < 32; k += 2) {
    body(xb0, AT, BT, bid + GRID * k,       lane, g, l15, x, bias, out);
    body(xb1, AT, BT, bid + GRID * (k + 1), lane, g, l15, x, bias, out);
  }
}

extern "C" void kernel_launch(void* const* d_in, const int* in_sizes, int n_in,
                              void* d_out, int out_size, void* d_ws, size_t ws_size,
                              hipStream_t stream) {
  const float* x    = (const float*)d_in[0];
  const float* A    = (const float*)d_in[1];
  const float* B    = (const float*)d_in[2];
  const float* bias = (const float*)d_in[3];
  float* out        = (float*)d_out;
  kron_kernel<<<dim3(GRID), dim3(64), 0, stream>>>(x, A, B, bias, out);
}